// Round 11
// baseline (155.707 us; speedup 1.0000x reference)
//
#include <hip/hip_runtime.h>
#include <hip/hip_bf16.h>

// Problem: B=8, N=4096, E=65536, D=256
// h = x@W^T + b; agg = segment_sum(h[src]*m_s*m_t by tgt); h += agg/64;
// out = relu(LN(h)*gamma+beta) * mask
#define NN 4096
#define DIM 256
#define NE 65536
#define TOT_NODES 32768
#define TOT_EDGES 524288

// ---- runtime-dtype accessors ------------------------------------------------------
__device__ __forceinline__ float ldf(const void* p, int isbf, size_t i) {
    return isbf ? __bfloat162float(((const __hip_bfloat16*)p)[i]) : ((const float*)p)[i];
}
__device__ __forceinline__ int ldi(const void* p, int is64, size_t i) {
    return is64 ? (int)((const long long*)p)[i] : ((const int*)p)[i];
}

typedef __attribute__((ext_vector_type(8))) __bf16 bf16x8;
typedef __attribute__((ext_vector_type(4))) float  f32x4;

__device__ __forceinline__ unsigned short f2bf(float f) {
    unsigned u = __float_as_uint(f);
    u = (u + 0x7fffu + ((u >> 16) & 1u)) >> 16;
    return (unsigned short)u;
}
__device__ __forceinline__ float bf2f(unsigned short h) {
    return __uint_as_float(((unsigned)h) << 16);
}
__device__ __forceinline__ void cvt_hilo(float4 f, ushort4* hi, ushort4* lo) {
    const unsigned short h0 = f2bf(f.x), h1 = f2bf(f.y), h2 = f2bf(f.z), h3 = f2bf(f.w);
    *hi = make_ushort4(h0, h1, h2, h3);
    *lo = make_ushort4(f2bf(f.x - bf2f(h0)), f2bf(f.y - bf2f(h1)),
                       f2bf(f.z - bf2f(h2)), f2bf(f.w - bf2f(h3)));
}
// swizzled ds_read_b128 of 8 bf16 at (row,col) in a [*][64]-bf16 LDS tile
__device__ __forceinline__ bf16x8 frag_ld(const unsigned short* base, int row, int col) {
    const int byte = ((row * 64 + col) * 2) ^ ((row & 7) << 4);
    return *(const bf16x8*)((const char*)base + byte);
}
__device__ __forceinline__ void gload16(const void* g, void* l) {
    __builtin_amdgcn_global_load_lds(
        (const __attribute__((address_space(1))) unsigned int*)g,
        (__attribute__((address_space(3))) unsigned int*)l, 16, 0, 0);
}

// ---- dtype detect (one wave; writes f3[0..2]); per-block, inputs are L2-hot -------
// f3[0]=edge_index int64, f3[1]=node_mask int64, f3[2]=floats bf16
__device__ __forceinline__ void detect_wave(const void* ei, const void* nm,
                                            const void* x, int* f3) {
    const int t = threadIdx.x;   // caller guarantees t < 64
    const long long ev = ((const long long*)ei)[t];
    const unsigned long long okE = __ballot(ev >= 0 && ev < NN);
    const long long mv = ((const long long*)nm)[t];
    const unsigned long long okM = __ballot(mv == 0 || mv == 1);
    const unsigned int w = ((const unsigned int*)x)[t];
    const int e = (w >> 7) & 0xFF;
    const unsigned long long okF = __ballot(e >= 100 && e <= 140);
    if (t == 0) {
        f3[0] = (okE == ~0ULL) ? 1 : 0;
        f3[1] = (okM == ~0ULL) ? 1 : 0;
        f3[2] = (__popcll(okF) >= 40) ? 1 : 0;
    }
}

// ---- edge fetch: 4 edges/thread, batch b, base edge k ----------------------------
__device__ __forceinline__ void edges4(const void* ei, int e64, int b, int k,
                                       int* s, int* tg) {
    const size_t eb = (size_t)b * 2 * NE;
    if (e64) {
        const longlong2 s01 = *(const longlong2*)((const long long*)ei + eb + k);
        const longlong2 s23 = *(const longlong2*)((const long long*)ei + eb + k + 2);
        const longlong2 t01 = *(const longlong2*)((const long long*)ei + eb + NE + k);
        const longlong2 t23 = *(const longlong2*)((const long long*)ei + eb + NE + k + 2);
        s[0]=(int)s01.x; s[1]=(int)s01.y; s[2]=(int)s23.x; s[3]=(int)s23.y;
        tg[0]=(int)t01.x; tg[1]=(int)t01.y; tg[2]=(int)t23.x; tg[3]=(int)t23.y;
    } else {
        const int4 sv = *(const int4*)((const int*)ei + eb + k);
        const int4 tv = *(const int4*)((const int*)ei + eb + NE + k);
        s[0]=sv.x; s[1]=sv.y; s[2]=sv.z; s[3]=sv.w;
        tg[0]=tv.x; tg[1]=tv.y; tg[2]=tv.z; tg[3]=tv.w;
    }
}
// ---- edge fetch: 2 edges/thread (1024-thread gemm blocks) ------------------------
__device__ __forceinline__ void edges2(const void* ei, int e64, int b, int k,
                                       int* s, int* tg) {
    const size_t eb = (size_t)b * 2 * NE;
    if (e64) {
        const longlong2 sv = *(const longlong2*)((const long long*)ei + eb + k);
        const longlong2 tv = *(const longlong2*)((const long long*)ei + eb + NE + k);
        s[0]=(int)sv.x; s[1]=(int)sv.y; tg[0]=(int)tv.x; tg[1]=(int)tv.y;
    } else {
        const int2 sv = *(const int2*)((const int*)ei + eb + k);
        const int2 tv = *(const int2*)((const int*)ei + eb + NE + k);
        s[0]=sv.x; s[1]=sv.y; tg[0]=tv.x; tg[1]=tv.y;
    }
}

// ---------------- gemm kernel (1024 thr) with in-block count tail ------------------
// Grid 256 x 1024 threads = 16 waves (2m x 8n; wave subtile 64x32, acc[4][2]=32 regs).
// R10 post-mortem: at 512 thr the 96 KB/1-block-CU config gives only 2 waves/SIMD --
// gemm was latency/store-drain-bound (44 us, 2.4 TB/s effective, MfmaUtil 10%).
// 1024 thr keeps 1 block/CU (96 KB LDS) and the SAME register model (16 waves/CU =
// 4 waves/SIMD -> 128-reg budget; acc 32 + frags 24 fits, no spill) but DOUBLES the
// latency-hiding TLP for staging waits and the 50 MB epilogue drain.
// LDS/swizzle/dataflow identical to the proven R9/R10 body (VGPR=120, 0 conflicts):
// tile 128(M) x 256(N=full D), BK=64, DOUBLE-buffered 96 KB. 96 KB is deliberate:
// smaller LDS makes the backend target >=2 blocks/CU and squeeze the register
// budget below the accumulator working set -> spills + scalarized ds_reads ->
// 7.08M bank conflicts (R7/R8).
// m0 XCD-remapped: block i (XCD i&7) computes batch i&7's rows -> h/hb16 slice is
// produced on the XCD whose node-phase blocks later gather it. Count tail: each
// block counts its own batch's 2048-edge slice (2/thread); loads hoisted BEFORE the
// K-loop (hidden under MFMA), atomics after the epilogue (overlap store drain);
// counts[b*NN+..] atomics stay on the owning XCD.
// bf16 path: global_load_lds w=16, pre-swizzled source (XOR (row&7)<<4 involution ->
// source group cg=(slot&7)^(row&7); linear LDS dest as HW requires); k-tile kt+1
// prefetch issued before compute of kt (1 barrier per k-tile).
// fp32 fallback: register staging hi/lo bf16 split (buffers 0=hi, 1=lo), 3-term MFMA.
// Epilogue writes fp32 h (self/LN path) + bf16 mirror (gather path; agg scaled by
// 1/64 so bf16 gather error is negligible).
__global__ __launch_bounds__(1024)
void gemm_count_kernel(const void* __restrict__ x, const void* __restrict__ w,
                       const void* __restrict__ bias,
                       const void* __restrict__ ei, const void* __restrict__ nm,
                       int* __restrict__ counts,
                       float* __restrict__ h, unsigned short* __restrict__ hb16)
{
    __shared__ int sflags[3];
    __shared__ unsigned short As[2][128 * 64];   // 2 x 16 KB
    __shared__ unsigned short Bs[2][256 * 64];   // 2 x 32 KB -> 96 KB total
    const int t = threadIdx.x;
    if (t < 64) detect_wave(ei, nm, x, sflags);
    __syncthreads();
    const int e64 = sflags[0], m64 = sflags[1], fbf = sflags[2];

    // ---- hoisted count loads (hidden under the K-loop) ----
    const int cb = (int)blockIdx.x & 7;            // count batch == m0 batch
    const int csub = (int)blockIdx.x >> 3;         // 0..31
    const int ck = ((csub << 10) + t) << 1;        // 2048 edges/block, 2/thread
    int es[2], et[2];
    edges2(ei, e64, cb, ck, es, et);
    const size_t cmb = (size_t)cb * NN;
    int cok = 0;
#pragma unroll
    for (int i = 0; i < 2; ++i)
        if (ldi(nm, m64, cmb + es[i]) && ldi(nm, m64, cmb + et[i])) cok |= (1 << i);

    // ---- gemm ----
    const int lane = t & 63;
    const int wid = t >> 6;         // 0..15
    const int wr = wid >> 3;        // m-half (64 rows)
    const int wc = wid & 7;         // n-eighth (32 cols)
    const int m0 = ((((int)blockIdx.x & 7) << 5) + ((int)blockIdx.x >> 3)) * 128;

    f32x4 acc[4][2];
#pragma unroll
    for (int mi = 0; mi < 4; ++mi)
#pragma unroll
        for (int nj = 0; nj < 2; ++nj)
            acc[mi][nj] = (f32x4){0.f, 0.f, 0.f, 0.f};

    const int lr = lane & 15;
    const int lk8 = (lane >> 4) << 3;

    auto compute_hh = [&](const unsigned short* Ab, const unsigned short* Bb) {
#pragma unroll
        for (int kk = 0; kk < 64; kk += 32) {
            const int lk = kk + lk8;
            bf16x8 aH[4], bH[2];
#pragma unroll
            for (int mi = 0; mi < 4; ++mi)
                aH[mi] = frag_ld(Ab, wr * 64 + mi * 16 + lr, lk);
#pragma unroll
            for (int nj = 0; nj < 2; ++nj)
                bH[nj] = frag_ld(Bb, wc * 32 + nj * 16 + lr, lk);
#pragma unroll
            for (int mi = 0; mi < 4; ++mi)
#pragma unroll
                for (int nj = 0; nj < 2; ++nj)
                    acc[mi][nj] = __builtin_amdgcn_mfma_f32_16x16x32_bf16(
                        aH[mi], bH[nj], acc[mi][nj], 0, 0, 0);
        }
    };

    if (fbf) {
        const unsigned short* xp = (const unsigned short*)x;
        const unsigned short* wp = (const unsigned short*)w;
        auto stage = [&](int kt, int buf) {
            const int k0 = kt * 64;
            {                                        // A: 1024 slots, 1/thread
                const int s = t;
                const int row = s >> 3, cgx = (s & 7) ^ (row & 7);
                gload16(xp + (size_t)(m0 + row) * 256 + k0 + cgx * 8, &As[buf][s * 8]);
            }
#pragma unroll
            for (int i = 0; i < 2; ++i) {            // B: 2048 slots, 2/thread
                const int s = i * 1024 + t;
                const int row = s >> 3, cgx = (s & 7) ^ (row & 7);
                gload16(wp + (size_t)row * 256 + k0 + cgx * 8, &Bs[buf][s * 8]);
            }
        };
        stage(0, 0);
        for (int kt = 0; kt < 4; ++kt) {
            __syncthreads();                           // drains vmcnt -> buf ready
            if (kt < 3) stage(kt + 1, (kt + 1) & 1);   // prefetch next
            compute_hh(As[kt & 1], Bs[kt & 1]);
        }
    } else {
        // fp32 fallback: buffers [0]=hi, [1]=lo, single-buffered, 3-term MFMA
        const float* xp = (const float*)x;
        const float* wp = (const float*)w;
        for (int kt = 0; kt < 4; ++kt) {
            const int k0 = kt * 64;
            {
                const int s = t;
                const int row = s >> 3, cgx = (s & 7) ^ (row & 7);
                const float* src = xp + (size_t)(m0 + row) * 256 + k0 + cgx * 8;
                const float4 f0 = *(const float4*)src, f1 = *(const float4*)(src + 4);
                ushort4 h0, l0, h1, l1;
                cvt_hilo(f0, &h0, &l0); cvt_hilo(f1, &h1, &l1);
                *(ushort4*)&As[0][s * 8]     = h0; *(ushort4*)&As[0][s * 8 + 4] = h1;
                *(ushort4*)&As[1][s * 8]     = l0; *(ushort4*)&As[1][s * 8 + 4] = l1;
            }
#pragma unroll
            for (int i = 0; i < 2; ++i) {
                const int s = i * 1024 + t;
                const int row = s >> 3, cgx = (s & 7) ^ (row & 7);
                const float* src = wp + (size_t)row * 256 + k0 + cgx * 8;
                const float4 f0 = *(const float4*)src, f1 = *(const float4*)(src + 4);
                ushort4 h0, l0, h1, l1;
                cvt_hilo(f0, &h0, &l0); cvt_hilo(f1, &h1, &l1);
                *(ushort4*)&Bs[0][s * 8]     = h0; *(ushort4*)&Bs[0][s * 8 + 4] = h1;
                *(ushort4*)&Bs[1][s * 8]     = l0; *(ushort4*)&Bs[1][s * 8 + 4] = l1;
            }
            __syncthreads();
            compute_hh(As[0], Bs[0]);
#pragma unroll
            for (int kk = 0; kk < 64; kk += 32) {
                const int lk = kk + lk8;
                bf16x8 aH[4], bH[2], aL[4], bL[2];
#pragma unroll
                for (int mi = 0; mi < 4; ++mi) {
                    aH[mi] = frag_ld(As[0], wr * 64 + mi * 16 + lr, lk);
                    aL[mi] = frag_ld(As[1], wr * 64 + mi * 16 + lr, lk);
                }
#pragma unroll
                for (int nj = 0; nj < 2; ++nj) {
                    bH[nj] = frag_ld(Bs[0], wc * 32 + nj * 16 + lr, lk);
                    bL[nj] = frag_ld(Bs[1], wc * 32 + nj * 16 + lr, lk);
                }
#pragma unroll
                for (int mi = 0; mi < 4; ++mi)
#pragma unroll
                    for (int nj = 0; nj < 2; ++nj) {
                        acc[mi][nj] = __builtin_amdgcn_mfma_f32_16x16x32_bf16(
                            aH[mi], bL[nj], acc[mi][nj], 0, 0, 0);
                        acc[mi][nj] = __builtin_amdgcn_mfma_f32_16x16x32_bf16(
                            aL[mi], bH[nj], acc[mi][nj], 0, 0, 0);
                    }
            }
            __syncthreads();
        }
    }

    // epilogue: +bias, fp32 h + bf16 mirror. C/D map: col=lane&15, row=(lane>>4)*4+r
    const int r4 = (lane >> 4) << 2;
#pragma unroll
    for (int nj = 0; nj < 2; ++nj) {
        const int n = wc * 32 + nj * 16 + lr;
        const float bv = ldf(bias, fbf, n);
#pragma unroll
        for (int mi = 0; mi < 4; ++mi) {
            const int rb = m0 + wr * 64 + mi * 16 + r4;
#pragma unroll
            for (int r = 0; r < 4; ++r) {
                const float v = acc[mi][nj][r] + bv;
                const size_t idx = (size_t)(rb + r) * 256 + n;
                h[idx] = v;
                hb16[idx] = f2bf(v);
            }
        }
    }

    // ---- count tail: atomics only (loads done pre-K-loop); overlaps store drain ----
#pragma unroll
    for (int i = 0; i < 2; ++i)
        if (cok & (1 << i))
            atomicAdd(&counts[cb * NN + et[i]], 1);
}

// ---------------- per-batch scan (8 blocks x 512, coalesced) -----------------------
// Bucket space partitioned at b*NE (per-batch active <= NE). offsets[]=start; the
// cursor copy becomes end-pointers after fill. Block b lands on XCD b (round-robin).
__global__ __launch_bounds__(512)
void scan_kernel(int* __restrict__ counts, int* __restrict__ offsets)
{
    __shared__ int sums[512];
    const int b = (int)blockIdx.x, t = (int)threadIdx.x;
    const int base = b * NN;
    int s = 0;
#pragma unroll
    for (int i = 0; i < 8; ++i) s += counts[base + i * 512 + t];
    sums[t] = s;
    __syncthreads();
    for (int off = 1; off < 512; off <<= 1) {
        int v = (t >= off) ? sums[t - off] : 0;
        __syncthreads();
        sums[t] += v;
        __syncthreads();
    }
    int run = b * NE + sums[t] - s;
#pragma unroll
    for (int i = 0; i < 8; ++i) {
        const int idx = base + i * 512 + t;
        const int c = counts[idx];
        offsets[idx] = run;
        counts[idx] = run;      // cursor init for fill
        run += c;
    }
}

// ---------------- fill (256 blocks x 512, 4 edges/thread, batch==XCD) --------------
__global__ __launch_bounds__(512)
void fill_kernel(const void* __restrict__ ei, const void* __restrict__ nm,
                 const void* __restrict__ x,
                 int* __restrict__ cursor, int* __restrict__ bucket)
{
    __shared__ int sflags[3];
    const int t = threadIdx.x;
    if (t < 64) detect_wave(ei, nm, x, sflags);
    __syncthreads();
    const int e64 = sflags[0], m64 = sflags[1];
    const int b = (int)blockIdx.x & 7, sub = (int)blockIdx.x >> 3;
    const int k = ((sub << 9) + t) << 2;
    int s[4], tg[4];
    edges4(ei, e64, b, k, s, tg);
    const size_t mb = (size_t)b * NN;
#pragma unroll
    for (int i = 0; i < 4; ++i)
        if (ldi(nm, m64, mb + s[i]) && ldi(nm, m64, mb + tg[i]))
            bucket[atomicAdd(&cursor[b * NN + tg[i]], 1)] = s[i];
}

// ---------------- node: gather + residual + LN + ReLU + mask -----------------------
// 8192 blocks x 256 thr = 4 waves/block, ONE node per wave (high occupancy for the
// latency-bound gather; the mono round proved 8-wave/CU starves this phase).
// Neighbor rows gathered from the bf16 mirror (512 B/row, ushort4/lane). Self + LN
// stay fp32. XCD swizzle: batch b's blocks on XCD b (2 MB bf16 slice fits 4 MB
// per-XCD L2, written there by the gemm role). Bijective (8192%8==0); perf-only.
__global__ __launch_bounds__(256)
void node_kernel(const float* __restrict__ h, const unsigned short* __restrict__ hb16,
                 const int* __restrict__ offsets, const int* __restrict__ ends,
                 const int* __restrict__ bucket,
                 const void* __restrict__ nm, const void* __restrict__ ei,
                 const void* __restrict__ x,
                 const void* __restrict__ gamma, const void* __restrict__ beta,
                 void* __restrict__ out)
{
    __shared__ int sflags[3];
    if (threadIdx.x < 64) detect_wave(ei, nm, x, sflags);
    __syncthreads();
    const int m64 = sflags[1], fbf = sflags[2];
    const int blk = (((int)blockIdx.x & 7) << 10) | ((int)blockIdx.x >> 3);
    const int bt = blk * 4 + ((int)threadIdx.x >> 6);
    const int lane = threadIdx.x & 63;
    const size_t o4 = (size_t)bt * 64 + lane;     // float4/ushort4 index
    if (!ldi(nm, m64, bt)) {
        if (fbf) ((ushort4*)out)[o4] = make_ushort4(0, 0, 0, 0);
        else     ((float4*)out)[o4]  = make_float4(0.f, 0.f, 0.f, 0.f);
        return;
    }
    const int b = bt >> 12;     // NN = 4096
    const ushort4* hg = (const ushort4*)hb16 + ((size_t)b << 12) * 64;
    const float4 self = ((const float4*)h)[o4];
    const int s0 = offsets[bt], s1 = ends[bt];
    float4 a0 = make_float4(0.f, 0.f, 0.f, 0.f), a1 = a0, a2 = a0, a3 = a0;
    int j = s0;
    for (; j + 4 <= s1; j += 4) {
        const ushort4 u0 = hg[(size_t)bucket[j]     * 64 + lane];
        const ushort4 u1 = hg[(size_t)bucket[j + 1] * 64 + lane];
        const ushort4 u2 = hg[(size_t)bucket[j + 2] * 64 + lane];
        const ushort4 u3 = hg[(size_t)bucket[j + 3] * 64 + lane];
        a0.x += bf2f(u0.x); a0.y += bf2f(u0.y); a0.z += bf2f(u0.z); a0.w += bf2f(u0.w);
        a1.x += bf2f(u1.x); a1.y += bf2f(u1.y); a1.z += bf2f(u1.z); a1.w += bf2f(u1.w);
        a2.x += bf2f(u2.x); a2.y += bf2f(u2.y); a2.z += bf2f(u2.z); a2.w += bf2f(u2.w);
        a3.x += bf2f(u3.x); a3.y += bf2f(u3.y); a3.z += bf2f(u3.z); a3.w += bf2f(u3.w);
    }
    for (; j < s1; ++j) {
        const ushort4 u = hg[(size_t)bucket[j] * 64 + lane];
        a0.x += bf2f(u.x); a0.y += bf2f(u.y); a0.z += bf2f(u.z); a0.w += bf2f(u.w);
    }
    float4 acc;
    acc.x = self.x + ((a0.x + a1.x) + (a2.x + a3.x)) * 0.015625f;  // /sqrt(4096)
    acc.y = self.y + ((a0.y + a1.y) + (a2.y + a3.y)) * 0.015625f;
    acc.z = self.z + ((a0.z + a1.z) + (a2.z + a3.z)) * 0.015625f;
    acc.w = self.w + ((a0.w + a1.w) + (a2.w + a3.w)) * 0.015625f;

    float v1r = (acc.x + acc.y) + (acc.z + acc.w);
    float v2r = (acc.x * acc.x + acc.y * acc.y) + (acc.z * acc.z + acc.w * acc.w);
#pragma unroll
    for (int off = 32; off > 0; off >>= 1) {
        v1r += __shfl_xor(v1r, off, 64);
        v2r += __shfl_xor(v2r, off, 64);
    }
    const float mu  = v1r * (1.f / 256.f);
    const float var = v2r * (1.f / 256.f) - mu * mu;
    const float inv = rsqrtf(var + 1e-5f);
    const int d0 = lane * 4;
    float y0 = fmaxf((acc.x - mu) * inv * ldf(gamma, fbf, d0)     + ldf(beta, fbf, d0),     0.f);
    float y1 = fmaxf((acc.y - mu) * inv * ldf(gamma, fbf, d0 + 1) + ldf(beta, fbf, d0 + 1), 0.f);
    float y2 = fmaxf((acc.z - mu) * inv * ldf(gamma, fbf, d0 + 2) + ldf(beta, fbf, d0 + 2), 0.f);
    float y3 = fmaxf((acc.w - mu) * inv * ldf(gamma, fbf, d0 + 3) + ldf(beta, fbf, d0 + 3), 0.f);
    if (fbf) ((ushort4*)out)[o4] = make_ushort4(f2bf(y0), f2bf(y1), f2bf(y2), f2bf(y3));
    else     ((float4*)out)[o4]  = make_float4(y0, y1, y2, y3);
}

// host-side sentinel buffer for launch-failure diagnosis (static lifetime: safe
// for async H2D copy; value encodes the first failing stage as absmax ~ 1e4*stage)
static float g_sentinel[256];

extern "C" void kernel_launch(void* const* d_in, const int* in_sizes, int n_in,
                              void* d_out, int out_size, void* d_ws, size_t ws_size,
                              hipStream_t stream)
{
    (void)in_sizes; (void)n_in; (void)out_size; (void)ws_size;
    const void* x     = d_in[0];
    const void* W     = d_in[1];
    const void* bias  = d_in[2];
    const void* gamma = d_in[3];
    const void* beta  = d_in[4];
    const void* ei    = d_in[5];
    const void* nm    = d_in[6];

    char* ws = (char*)d_ws;
    int* counts  = (int*)(ws + 256);           // @256      131072 B (cursor/end after fill)
    int* offsets = (int*)(ws + 131328);        // @131328   131072 B
    int* bucket  = (int*)(ws + 262656);        // @262656   2097152 B
    float* h     = (float*)(ws + 2359808);     // @2359808  33554432 B (fp32 h)
    unsigned short* hb16 = (unsigned short*)(ws + 35914240);  // @35914240 16777216 B

    int fail = 0;
    hipGetLastError();   // clear pre-existing error
#define CHK(stage) do { if (!fail && hipGetLastError() != hipSuccess) fail = (stage); } while (0)

    if (hipMemsetAsync(counts, 0, TOT_NODES * sizeof(int), stream) != hipSuccess)
        fail = 1;
    gemm_count_kernel<<<256, 1024, 0, stream>>>(x, W, bias, ei, nm, counts, h, hb16);
    CHK(2);
    scan_kernel<<<8, 512, 0, stream>>>(counts, offsets);                         CHK(3);
    fill_kernel<<<256, 512, 0, stream>>>(ei, nm, x, counts, bucket);             CHK(4);
    node_kernel<<<8192, 256, 0, stream>>>(h, hb16, offsets, counts, bucket,
                                          nm, ei, x, gamma, beta, d_out);        CHK(5);
#undef CHK

    if (fail) {   // deterministic per-environment -> graph-capture safe
        for (int i = 0; i < 256; ++i) g_sentinel[i] = 10000.f * (float)fail;
        hipMemcpyAsync(d_out, g_sentinel, sizeof(g_sentinel),
                       hipMemcpyHostToDevice, stream);
    }
}

// Round 12
// 152.099 us; speedup vs baseline: 1.0237x; 1.0237x over previous
//
#include <hip/hip_runtime.h>
#include <hip/hip_bf16.h>

// Problem: B=8, N=4096, E=65536, D=256
// h = x@W^T + b; agg = segment_sum(h[src]*m_s*m_t by tgt); h += agg/64;
// out = relu(LN(h)*gamma+beta) * mask
#define NN 4096
#define DIM 256
#define NE 65536
#define TOT_NODES 32768
#define TOT_EDGES 524288

// ---- runtime-dtype accessors ------------------------------------------------------
__device__ __forceinline__ float ldf(const void* p, int isbf, size_t i) {
    return isbf ? __bfloat162float(((const __hip_bfloat16*)p)[i]) : ((const float*)p)[i];
}
__device__ __forceinline__ int ldi(const void* p, int is64, size_t i) {
    return is64 ? (int)((const long long*)p)[i] : ((const int*)p)[i];
}

typedef __attribute__((ext_vector_type(8))) __bf16 bf16x8;
typedef __attribute__((ext_vector_type(4))) float  f32x4;

__device__ __forceinline__ unsigned short f2bf(float f) {
    unsigned u = __float_as_uint(f);
    u = (u + 0x7fffu + ((u >> 16) & 1u)) >> 16;
    return (unsigned short)u;
}
__device__ __forceinline__ float bf2f(unsigned short h) {
    return __uint_as_float(((unsigned)h) << 16);
}
// fp16 pack/unpack (v_cvt_f16_f32 / v_cvt_f32_f16)
__device__ __forceinline__ unsigned short f2h(float f) {
    _Float16 h = (_Float16)f;
    unsigned short u;
    __builtin_memcpy(&u, &h, 2);
    return u;
}
__device__ __forceinline__ float h2f(unsigned short u) {
    _Float16 h;
    __builtin_memcpy(&h, &u, 2);
    return (float)h;
}
__device__ __forceinline__ void cvt_hilo(float4 f, ushort4* hi, ushort4* lo) {
    const unsigned short h0 = f2bf(f.x), h1 = f2bf(f.y), h2 = f2bf(f.z), h3 = f2bf(f.w);
    *hi = make_ushort4(h0, h1, h2, h3);
    *lo = make_ushort4(f2bf(f.x - bf2f(h0)), f2bf(f.y - bf2f(h1)),
                       f2bf(f.z - bf2f(h2)), f2bf(f.w - bf2f(h3)));
}
// swizzled ds_read_b128 of 8 bf16 at (row,col) in a [*][64]-bf16 LDS tile
__device__ __forceinline__ bf16x8 frag_ld(const unsigned short* base, int row, int col) {
    const int byte = ((row * 64 + col) * 2) ^ ((row & 7) << 4);
    return *(const bf16x8*)((const char*)base + byte);
}
__device__ __forceinline__ void gload16(const void* g, void* l) {
    __builtin_amdgcn_global_load_lds(
        (const __attribute__((address_space(1))) unsigned int*)g,
        (__attribute__((address_space(3))) unsigned int*)l, 16, 0, 0);
}

// ---- dtype detect (one wave; writes f3[0..2]); per-block, inputs are L2-hot -------
// f3[0]=edge_index int64, f3[1]=node_mask int64, f3[2]=floats bf16
__device__ __forceinline__ void detect_wave(const void* ei, const void* nm,
                                            const void* x, int* f3) {
    const int t = threadIdx.x;   // caller guarantees t < 64
    const long long ev = ((const long long*)ei)[t];
    const unsigned long long okE = __ballot(ev >= 0 && ev < NN);
    const long long mv = ((const long long*)nm)[t];
    const unsigned long long okM = __ballot(mv == 0 || mv == 1);
    const unsigned int w = ((const unsigned int*)x)[t];
    const int e = (w >> 7) & 0xFF;
    const unsigned long long okF = __ballot(e >= 100 && e <= 140);
    if (t == 0) {
        f3[0] = (okE == ~0ULL) ? 1 : 0;
        f3[1] = (okM == ~0ULL) ? 1 : 0;
        f3[2] = (__popcll(okF) >= 40) ? 1 : 0;
    }
}

// ---- edge fetch: 4 edges/thread, batch b, base edge k ----------------------------
__device__ __forceinline__ void edges4(const void* ei, int e64, int b, int k,
                                       int* s, int* tg) {
    const size_t eb = (size_t)b * 2 * NE;
    if (e64) {
        const longlong2 s01 = *(const longlong2*)((const long long*)ei + eb + k);
        const longlong2 s23 = *(const longlong2*)((const long long*)ei + eb + k + 2);
        const longlong2 t01 = *(const longlong2*)((const long long*)ei + eb + NE + k);
        const longlong2 t23 = *(const longlong2*)((const long long*)ei + eb + NE + k + 2);
        s[0]=(int)s01.x; s[1]=(int)s01.y; s[2]=(int)s23.x; s[3]=(int)s23.y;
        tg[0]=(int)t01.x; tg[1]=(int)t01.y; tg[2]=(int)t23.x; tg[3]=(int)t23.y;
    } else {
        const int4 sv = *(const int4*)((const int*)ei + eb + k);
        const int4 tv = *(const int4*)((const int*)ei + eb + NE + k);
        s[0]=sv.x; s[1]=sv.y; s[2]=sv.z; s[3]=sv.w;
        tg[0]=tv.x; tg[1]=tv.y; tg[2]=tv.z; tg[3]=tv.w;
    }
}

// ---------------- gemm kernel (512 thr, R10 geometry) with in-block count tail -----
// Grid 256 x 512. This is the ONLY proven-clean compile point for this body
// (R9/R10: VGPR=120, 0 bank conflicts): 512 thr + 96 KB LDS -> 1 block/CU ->
// full register budget. R7/R8 (48 KB) and R11 (1024 thr) both tripped the
// backend's occupancy heuristic into a 64-VGPR cap -> spills -> 7M conflicts /
// scratch thrash. Do not change threads or LDS size.
// R12 change: h is stored as ONE fp16 array (self + gather both read it).
//  - fp16 err = 2^-11 rel (8x tighter than the bf16 mirror we already gathered
//    from); self-path error <= ~0.003, invisible at 0.0156 absmax.
//  - gemm writes 16.8 MB instead of 50.3 (fp32 h + bf16 mirror), and R10's
//    WRITE_SIZE showed 83 MB (32B-segment write amplification on the mirror).
//  - LDS-STAGED EPILOGUE kills the amplification: after the K-loop the 96 KB
//    LDS is dead; convert acc->fp16 into a 64 KB LDS tile (barrier-protected
//    reuse), then flush as a contiguous 64 KB memcpy (uint4 full lines).
// fp32-input fallback keeps fp32 h + direct stores (node reads self fp32 there).
// m0 XCD-remapped: block i (XCD i&7) computes batch i&7's rows -> h slice is
// produced on the XCD whose node-phase blocks later gather it. Count tail: each
// block counts its own batch's 2048-edge slice (4/thread); loads hoisted BEFORE
// the K-loop (hidden under MFMA), atomics after the epilogue; counts[b*NN+..]
// atomics stay on the owning XCD.
// bf16 path: global_load_lds w=16, pre-swizzled source (XOR (row&7)<<4 is an
// involution -> source group cg=(slot&7)^(row&7); linear LDS dest as HW
// requires); k-tile kt+1 prefetch issued before compute of kt.
__global__ __launch_bounds__(512)
void gemm_count_kernel(const void* __restrict__ x, const void* __restrict__ w,
                       const void* __restrict__ bias,
                       const void* __restrict__ ei, const void* __restrict__ nm,
                       int* __restrict__ counts,
                       float* __restrict__ h, unsigned short* __restrict__ hf16)
{
    __shared__ int sflags[3];
    __shared__ __align__(16) char smem[98304];                       // 96 KB
    unsigned short (*As)[128 * 64] =
        reinterpret_cast<unsigned short(*)[128 * 64]>(smem);          // 2 x 16 KB
    unsigned short (*Bs)[256 * 64] =
        reinterpret_cast<unsigned short(*)[256 * 64]>(smem + 32768);  // 2 x 32 KB
    unsigned short* Ls = reinterpret_cast<unsigned short*>(smem);     // 64 KB reuse

    const int t = threadIdx.x;
    if (t < 64) detect_wave(ei, nm, x, sflags);
    __syncthreads();
    const int e64 = sflags[0], m64 = sflags[1], fbf = sflags[2];

    // ---- hoisted count loads (hidden under the K-loop) ----
    const int cb = (int)blockIdx.x & 7;            // count batch == m0 batch
    const int csub = (int)blockIdx.x >> 3;         // 0..31
    const int ck = ((csub << 9) + t) << 2;         // 2048 edges/block, 4/thread
    int es[4], et[4];
    edges4(ei, e64, cb, ck, es, et);
    const size_t cmb = (size_t)cb * NN;
    int cok = 0;
#pragma unroll
    for (int i = 0; i < 4; ++i)
        if (ldi(nm, m64, cmb + es[i]) && ldi(nm, m64, cmb + et[i])) cok |= (1 << i);

    // ---- gemm ----
    const int lane = t & 63;
    const int wid = t >> 6;
    const int wr = wid >> 2;        // m-half (64 rows)
    const int wc = wid & 3;         // n-quarter (64 cols)
    const int m0 = ((((int)blockIdx.x & 7) << 5) + ((int)blockIdx.x >> 3)) * 128;

    f32x4 acc[4][4];
#pragma unroll
    for (int mi = 0; mi < 4; ++mi)
#pragma unroll
        for (int nj = 0; nj < 4; ++nj)
            acc[mi][nj] = (f32x4){0.f, 0.f, 0.f, 0.f};

    const int lr = lane & 15;
    const int lk8 = (lane >> 4) << 3;

    auto compute_hh = [&](const unsigned short* Ab, const unsigned short* Bb) {
#pragma unroll
        for (int kk = 0; kk < 64; kk += 32) {
            const int lk = kk + lk8;
            bf16x8 aH[4], bH[4];
#pragma unroll
            for (int mi = 0; mi < 4; ++mi)
                aH[mi] = frag_ld(Ab, wr * 64 + mi * 16 + lr, lk);
#pragma unroll
            for (int nj = 0; nj < 4; ++nj)
                bH[nj] = frag_ld(Bb, wc * 64 + nj * 16 + lr, lk);
#pragma unroll
            for (int mi = 0; mi < 4; ++mi)
#pragma unroll
                for (int nj = 0; nj < 4; ++nj)
                    acc[mi][nj] = __builtin_amdgcn_mfma_f32_16x16x32_bf16(
                        aH[mi], bH[nj], acc[mi][nj], 0, 0, 0);
        }
    };

    if (fbf) {
        const unsigned short* xp = (const unsigned short*)x;
        const unsigned short* wp = (const unsigned short*)w;
        auto stage = [&](int kt, int buf) {
            const int k0 = kt * 64;
#pragma unroll
            for (int i = 0; i < 2; ++i) {           // A: 1024 slots, 2/thread
                const int s = i * 512 + t;
                const int row = s >> 3, cgx = (s & 7) ^ (row & 7);
                gload16(xp + (size_t)(m0 + row) * 256 + k0 + cgx * 8, &As[buf][s * 8]);
            }
#pragma unroll
            for (int i = 0; i < 4; ++i) {           // B: 2048 slots, 4/thread
                const int s = i * 512 + t;
                const int row = s >> 3, cgx = (s & 7) ^ (row & 7);
                gload16(wp + (size_t)row * 256 + k0 + cgx * 8, &Bs[buf][s * 8]);
            }
        };
        stage(0, 0);
        for (int kt = 0; kt < 4; ++kt) {
            __syncthreads();                           // drains vmcnt -> buf ready
            if (kt < 3) stage(kt + 1, (kt + 1) & 1);   // prefetch next
            compute_hh(As[kt & 1], Bs[kt & 1]);
        }

        // ---- LDS-staged epilogue: acc -> fp16 Ls (true layout) -> contiguous flush
        __syncthreads();   // all waves done reading As/Bs before Ls overwrite
        const int r4 = (lane >> 4) << 2;
#pragma unroll
        for (int nj = 0; nj < 4; ++nj) {
            const int n = wc * 64 + nj * 16 + lr;
            const float bv = ldf(bias, fbf, n);
#pragma unroll
            for (int mi = 0; mi < 4; ++mi) {
                const int lrow = wr * 64 + mi * 16 + r4;
#pragma unroll
                for (int r = 0; r < 4; ++r)
                    Ls[(lrow + r) * 256 + n] = f2h(acc[mi][nj][r] + bv);
            }
        }
        __syncthreads();
        // block's rows are contiguous in global: 128 rows x 256 x 2B = 64 KB memcpy
        unsigned short* gdst = hf16 + (size_t)m0 * 256;
#pragma unroll
        for (int i = 0; i < 8; ++i) {              // 4096 x 16B chunks, 8/thread
            const int c = i * 512 + t;
            *(uint4*)(gdst + c * 8) = *(const uint4*)(Ls + c * 8);
        }
    } else {
        // fp32 fallback: buffers [0]=hi, [1]=lo, single-buffered, 3-term MFMA
        const float* xp = (const float*)x;
        const float* wp = (const float*)w;
        for (int kt = 0; kt < 4; ++kt) {
            const int k0 = kt * 64;
#pragma unroll
            for (int i = 0; i < 2; ++i) {
                const int s = i * 512 + t;
                const int row = s >> 3, cgx = (s & 7) ^ (row & 7);
                const float* src = xp + (size_t)(m0 + row) * 256 + k0 + cgx * 8;
                const float4 f0 = *(const float4*)src, f1 = *(const float4*)(src + 4);
                ushort4 h0, l0, h1, l1;
                cvt_hilo(f0, &h0, &l0); cvt_hilo(f1, &h1, &l1);
                *(ushort4*)&As[0][s * 8]     = h0; *(ushort4*)&As[0][s * 8 + 4] = h1;
                *(ushort4*)&As[1][s * 8]     = l0; *(ushort4*)&As[1][s * 8 + 4] = l1;
            }
#pragma unroll
            for (int i = 0; i < 4; ++i) {
                const int s = i * 512 + t;
                const int row = s >> 3, cgx = (s & 7) ^ (row & 7);
                const float* src = wp + (size_t)row * 256 + k0 + cgx * 8;
                const float4 f0 = *(const float4*)src, f1 = *(const float4*)(src + 4);
                ushort4 h0, l0, h1, l1;
                cvt_hilo(f0, &h0, &l0); cvt_hilo(f1, &h1, &l1);
                *(ushort4*)&Bs[0][s * 8]     = h0; *(ushort4*)&Bs[0][s * 8 + 4] = h1;
                *(ushort4*)&Bs[1][s * 8]     = l0; *(ushort4*)&Bs[1][s * 8 + 4] = l1;
            }
            __syncthreads();
            compute_hh(As[0], Bs[0]);
#pragma unroll
            for (int kk = 0; kk < 64; kk += 32) {
                const int lk = kk + lk8;
                bf16x8 aH[4], bH[4], aL[4], bL[4];
#pragma unroll
                for (int mi = 0; mi < 4; ++mi) {
                    aH[mi] = frag_ld(As[0], wr * 64 + mi * 16 + lr, lk);
                    aL[mi] = frag_ld(As[1], wr * 64 + mi * 16 + lr, lk);
                }
#pragma unroll
                for (int nj = 0; nj < 4; ++nj) {
                    bH[nj] = frag_ld(Bs[0], wc * 64 + nj * 16 + lr, lk);
                    bL[nj] = frag_ld(Bs[1], wc * 64 + nj * 16 + lr, lk);
                }
#pragma unroll
                for (int mi = 0; mi < 4; ++mi)
#pragma unroll
                    for (int nj = 0; nj < 4; ++nj) {
                        acc[mi][nj] = __builtin_amdgcn_mfma_f32_16x16x32_bf16(
                            aH[mi], bL[nj], acc[mi][nj], 0, 0, 0);
                        acc[mi][nj] = __builtin_amdgcn_mfma_f32_16x16x32_bf16(
                            aL[mi], bH[nj], acc[mi][nj], 0, 0, 0);
                    }
            }
            __syncthreads();
        }
        // direct epilogue (fallback only): fp32 h + fp16 mirror
        const int r4 = (lane >> 4) << 2;
#pragma unroll
        for (int nj = 0; nj < 4; ++nj) {
            const int n = wc * 64 + nj * 16 + lr;
            const float bv = ldf(bias, fbf, n);
#pragma unroll
            for (int mi = 0; mi < 4; ++mi) {
                const int rb = m0 + wr * 64 + mi * 16 + r4;
#pragma unroll
                for (int r = 0; r < 4; ++r) {
                    const float v = acc[mi][nj][r] + bv;
                    const size_t idx = (size_t)(rb + r) * 256 + n;
                    h[idx] = v;
                    hf16[idx] = f2h(v);
                }
            }
        }
    }

    // ---- count tail: atomics only (loads done pre-K-loop); overlaps store drain ----
#pragma unroll
    for (int i = 0; i < 4; ++i)
        if (cok & (1 << i))
            atomicAdd(&counts[cb * NN + et[i]], 1);
}

// ---------------- per-batch scan (8 blocks x 512, coalesced) -----------------------
// Bucket space partitioned at b*NE (per-batch active <= NE). offsets[]=start; the
// cursor copy becomes end-pointers after fill. Block b lands on XCD b (round-robin).
__global__ __launch_bounds__(512)
void scan_kernel(int* __restrict__ counts, int* __restrict__ offsets)
{
    __shared__ int sums[512];
    const int b = (int)blockIdx.x, t = (int)threadIdx.x;
    const int base = b * NN;
    int s = 0;
#pragma unroll
    for (int i = 0; i < 8; ++i) s += counts[base + i * 512 + t];
    sums[t] = s;
    __syncthreads();
    for (int off = 1; off < 512; off <<= 1) {
        int v = (t >= off) ? sums[t - off] : 0;
        __syncthreads();
        sums[t] += v;
        __syncthreads();
    }
    int run = b * NE + sums[t] - s;
#pragma unroll
    for (int i = 0; i < 8; ++i) {
        const int idx = base + i * 512 + t;
        const int c = counts[idx];
        offsets[idx] = run;
        counts[idx] = run;      // cursor init for fill
        run += c;
    }
}

// ---------------- fill (256 blocks x 512, 4 edges/thread, batch==XCD) --------------
__global__ __launch_bounds__(512)
void fill_kernel(const void* __restrict__ ei, const void* __restrict__ nm,
                 const void* __restrict__ x,
                 int* __restrict__ cursor, int* __restrict__ bucket)
{
    __shared__ int sflags[3];
    const int t = threadIdx.x;
    if (t < 64) detect_wave(ei, nm, x, sflags);
    __syncthreads();
    const int e64 = sflags[0], m64 = sflags[1];
    const int b = (int)blockIdx.x & 7, sub = (int)blockIdx.x >> 3;
    const int k = ((sub << 9) + t) << 2;
    int s[4], tg[4];
    edges4(ei, e64, b, k, s, tg);
    const size_t mb = (size_t)b * NN;
#pragma unroll
    for (int i = 0; i < 4; ++i)
        if (ldi(nm, m64, mb + s[i]) && ldi(nm, m64, mb + tg[i]))
            bucket[atomicAdd(&cursor[b * NN + tg[i]], 1)] = s[i];
}

// ---------------- node: gather + residual + LN + ReLU + mask -----------------------
// 8192 blocks x 256 thr = 4 waves/block, ONE node per wave (high occupancy for the
// latency-bound gather). Self AND neighbor rows read from the fp16 h (512 B/row,
// ushort4/lane; fp16 err 2^-11 rel -> invisible). LN math in fp32. fp32-env
// fallback reads self from the fp32 h. XCD swizzle: batch b's blocks on XCD b
// (2 MB fp16 slice fits 4 MB per-XCD L2, written there by the gemm phase).
// Bijective (8192%8==0); perf-only heuristic.
__global__ __launch_bounds__(256)
void node_kernel(const float* __restrict__ h, const unsigned short* __restrict__ hf16,
                 const int* __restrict__ offsets, const int* __restrict__ ends,
                 const int* __restrict__ bucket,
                 const void* __restrict__ nm, const void* __restrict__ ei,
                 const void* __restrict__ x,
                 const void* __restrict__ gamma, const void* __restrict__ beta,
                 void* __restrict__ out)
{
    __shared__ int sflags[3];
    if (threadIdx.x < 64) detect_wave(ei, nm, x, sflags);
    __syncthreads();
    const int m64 = sflags[1], fbf = sflags[2];
    const int blk = (((int)blockIdx.x & 7) << 10) | ((int)blockIdx.x >> 3);
    const int bt = blk * 4 + ((int)threadIdx.x >> 6);
    const int lane = threadIdx.x & 63;
    const size_t o4 = (size_t)bt * 64 + lane;     // float4/ushort4 index
    if (!ldi(nm, m64, bt)) {
        if (fbf) ((ushort4*)out)[o4] = make_ushort4(0, 0, 0, 0);
        else     ((float4*)out)[o4]  = make_float4(0.f, 0.f, 0.f, 0.f);
        return;
    }
    const int b = bt >> 12;     // NN = 4096
    const ushort4* hg = (const ushort4*)hf16 + ((size_t)b << 12) * 64;
    float4 self;
    if (fbf) {
        const ushort4 sh = ((const ushort4*)hf16)[o4];
        self = make_float4(h2f(sh.x), h2f(sh.y), h2f(sh.z), h2f(sh.w));
    } else {
        self = ((const float4*)h)[o4];
    }
    const int s0 = offsets[bt], s1 = ends[bt];
    float4 a0 = make_float4(0.f, 0.f, 0.f, 0.f), a1 = a0, a2 = a0, a3 = a0;
    int j = s0;
    for (; j + 4 <= s1; j += 4) {
        const ushort4 u0 = hg[(size_t)bucket[j]     * 64 + lane];
        const ushort4 u1 = hg[(size_t)bucket[j + 1] * 64 + lane];
        const ushort4 u2 = hg[(size_t)bucket[j + 2] * 64 + lane];
        const ushort4 u3 = hg[(size_t)bucket[j + 3] * 64 + lane];
        a0.x += h2f(u0.x); a0.y += h2f(u0.y); a0.z += h2f(u0.z); a0.w += h2f(u0.w);
        a1.x += h2f(u1.x); a1.y += h2f(u1.y); a1.z += h2f(u1.z); a1.w += h2f(u1.w);
        a2.x += h2f(u2.x); a2.y += h2f(u2.y); a2.z += h2f(u2.z); a2.w += h2f(u2.w);
        a3.x += h2f(u3.x); a3.y += h2f(u3.y); a3.z += h2f(u3.z); a3.w += h2f(u3.w);
    }
    for (; j < s1; ++j) {
        const ushort4 u = hg[(size_t)bucket[j] * 64 + lane];
        a0.x += h2f(u.x); a0.y += h2f(u.y); a0.z += h2f(u.z); a0.w += h2f(u.w);
    }
    float4 acc;
    acc.x = self.x + ((a0.x + a1.x) + (a2.x + a3.x)) * 0.015625f;  // /sqrt(4096)
    acc.y = self.y + ((a0.y + a1.y) + (a2.y + a3.y)) * 0.015625f;
    acc.z = self.z + ((a0.z + a1.z) + (a2.z + a3.z)) * 0.015625f;
    acc.w = self.w + ((a0.w + a1.w) + (a2.w + a3.w)) * 0.015625f;

    float v1r = (acc.x + acc.y) + (acc.z + acc.w);
    float v2r = (acc.x * acc.x + acc.y * acc.y) + (acc.z * acc.z + acc.w * acc.w);
#pragma unroll
    for (int off = 32; off > 0; off >>= 1) {
        v1r += __shfl_xor(v1r, off, 64);
        v2r += __shfl_xor(v2r, off, 64);
    }
    const float mu  = v1r * (1.f / 256.f);
    const float var = v2r * (1.f / 256.f) - mu * mu;
    const float inv = rsqrtf(var + 1e-5f);
    const int d0 = lane * 4;
    float y0 = fmaxf((acc.x - mu) * inv * ldf(gamma, fbf, d0)     + ldf(beta, fbf, d0),     0.f);
    float y1 = fmaxf((acc.y - mu) * inv * ldf(gamma, fbf, d0 + 1) + ldf(beta, fbf, d0 + 1), 0.f);
    float y2 = fmaxf((acc.z - mu) * inv * ldf(gamma, fbf, d0 + 2) + ldf(beta, fbf, d0 + 2), 0.f);
    float y3 = fmaxf((acc.w - mu) * inv * ldf(gamma, fbf, d0 + 3) + ldf(beta, fbf, d0 + 3), 0.f);
    if (fbf) ((ushort4*)out)[o4] = make_ushort4(f2bf(y0), f2bf(y1), f2bf(y2), f2bf(y3));
    else     ((float4*)out)[o4]  = make_float4(y0, y1, y2, y3);
}

// host-side sentinel buffer for launch-failure diagnosis (static lifetime: safe
// for async H2D copy; value encodes the first failing stage as absmax ~ 1e4*stage)
static float g_sentinel[256];

extern "C" void kernel_launch(void* const* d_in, const int* in_sizes, int n_in,
                              void* d_out, int out_size, void* d_ws, size_t ws_size,
                              hipStream_t stream)
{
    (void)in_sizes; (void)n_in; (void)out_size; (void)ws_size;
    const void* x     = d_in[0];
    const void* W     = d_in[1];
    const void* bias  = d_in[2];
    const void* gamma = d_in[3];
    const void* beta  = d_in[4];
    const void* ei    = d_in[5];
    const void* nm    = d_in[6];

    char* ws = (char*)d_ws;
    int* counts  = (int*)(ws + 256);           // @256      131072 B (cursor/end after fill)
    int* offsets = (int*)(ws + 131328);        // @131328   131072 B
    int* bucket  = (int*)(ws + 262656);        // @262656   2097152 B
    float* h     = (float*)(ws + 2359808);     // @2359808  33554432 B (fp32 h, fallback path)
    unsigned short* hf16 = (unsigned short*)(ws + 35914240);  // @35914240 16777216 B (fp16 h)

    int fail = 0;
    hipGetLastError();   // clear pre-existing error
#define CHK(stage) do { if (!fail && hipGetLastError() != hipSuccess) fail = (stage); } while (0)

    if (hipMemsetAsync(counts, 0, TOT_NODES * sizeof(int), stream) != hipSuccess)
        fail = 1;
    gemm_count_kernel<<<256, 512, 0, stream>>>(x, W, bias, ei, nm, counts, h, hf16);
    CHK(2);
    scan_kernel<<<8, 512, 0, stream>>>(counts, offsets);                         CHK(3);
    fill_kernel<<<256, 512, 0, stream>>>(ei, nm, x, counts, bucket);             CHK(4);
    node_kernel<<<8192, 256, 0, stream>>>(h, hf16, offsets, counts, bucket,
                                          nm, ei, x, gamma, beta, d_out);        CHK(5);
#undef CHK

    if (fail) {   // deterministic per-environment -> graph-capture safe
        for (int i = 0; i < 256; ++i) g_sentinel[i] = 10000.f * (float)fail;
        hipMemcpyAsync(d_out, g_sentinel, sizeof(g_sentinel),
                       hipMemcpyHostToDevice, stream);
    }
}